// Round 3
// baseline (425.928 us; speedup 1.0000x reference)
//
#include <hip/hip_runtime.h>
#include <hip/hip_bf16.h>
#include <stdint.h>

// Problem constants
#define BQ 128    // batch
#define NJ 512    // input capsules j
#define DD 300    // input dim
#define NC 10     // num_capsule i
#define DC 64     // dim_capsule k
#define MM 640    // NC*DC
#define KP 320    // K padded (mult of 64)
#define RT 5      // routing iterations

typedef __attribute__((ext_vector_type(8))) short short8;
typedef __attribute__((ext_vector_type(4))) float f32x4;

__device__ inline float bf2f(ushort u) { return __uint_as_float((uint)u << 16); }

// ---------------- cast kernels (unchanged) ----------------

__global__ void k_cast_x(const float* __restrict__ x, __hip_bfloat16* __restrict__ xb) {
    int g = blockIdx.x * 256 + threadIdx.x;      // 65536*40 groups
    int row = g / 40, cg2 = g - row * 40;
    const float* src = x + (size_t)row * DD + cg2 * 8;
    float4 a = make_float4(0.f, 0.f, 0.f, 0.f), b4 = a;
    if (cg2 < 37) { a = *(const float4*)src; b4 = *(const float4*)(src + 4); }
    else if (cg2 == 37) { a = *(const float4*)src; }
    union { ushort u[8]; uint4 v; } o;
    float f[8] = {a.x, a.y, a.z, a.w, b4.x, b4.y, b4.z, b4.w};
#pragma unroll
    for (int e = 0; e < 8; ++e) {
        __hip_bfloat16 hh = __float2bfloat16(f[e]);
        o.u[e] = *(ushort*)&hh;
    }
    *(uint4*)(xb + (size_t)row * KP + cg2 * 8) = o.v;
}

__global__ void k_cast_w(const float* __restrict__ w, __hip_bfloat16* __restrict__ wt) {
    int idx = blockIdx.x * 256 + threadIdx.x;
    int m = idx / KP, k = idx - m * KP;
    float v = (k < DD) ? w[(size_t)k * MM + m] : 0.f;
    wt[idx] = __float2bfloat16(v);
}

__global__ void k_zero(float4* __restrict__ p) {   // zero sx (ws re-poisoned each call)
    p[blockIdx.x * 256 + threadIdx.x] = make_float4(0.f, 0.f, 0.f, 0.f);
}

// ---------------- transpose xb -> xt, fused column-sum sx ----------------
// block = (b, jt 0..7, dt 0..4): 64j x 64d tile. sx[b][d] = sum_j x[b,j,d].

__global__ __launch_bounds__(256)
void k_xt(const __hip_bfloat16* __restrict__ xb, __hip_bfloat16* __restrict__ xt,
          float* __restrict__ sx) {
    __shared__ ushort lt[64][76];                 // pitch 76 u16 = 152B (b64-aligned)
    int blk = blockIdx.x;
    int b = blk / 40, rem = blk - b * 40, jt = rem / 5, dt = rem - (rem / 5) * 5;
    int t = threadIdx.x;
    int r = t >> 2, c = t & 3;
#pragma unroll
    for (int h = 0; h < 2; ++h) {
        uint4 v = *(const uint4*)((const ushort*)xb +
            (size_t)(b * 512 + jt * 64 + r) * KP + dt * 64 + (c + 4 * h) * 8);
        *(uint2*)&lt[r][(c + 4 * h) * 8]     = make_uint2(v.x, v.y);
        *(uint2*)&lt[r][(c + 4 * h) * 8 + 4] = make_uint2(v.z, v.w);
    }
    __syncthreads();
    int dr = t >> 2;
    float s = 0.f;
#pragma unroll
    for (int h = 0; h < 2; ++h) {
        int jc = c + 4 * h;
        union { ushort u[8]; uint4 v; } o;
#pragma unroll
        for (int e = 0; e < 8; ++e) o.u[e] = lt[jc * 8 + e][dr];
        *(uint4*)((ushort*)xt + (size_t)(b * KP + dt * 64 + dr) * 512 + jt * 64 + jc * 8) = o.v;
#pragma unroll
        for (int e = 0; e < 8; ++e) s += bf2f(o.u[e]);
    }
    s += __shfl_xor(s, 1, 64);
    s += __shfl_xor(s, 2, 64);
    if (c == 0) atomicAdd(&sx[b * KP + dt * 64 + dr], s);
}

// ---------------- routing pass: bl-MFMA -> softmax -> Cx-MFMA ----------------
// block = (b, jb 0..7) covering 64 j; 256 threads = 4 waves, wave w owns j-tile
// j0 = jb*64 + w*16.  bl[i',j] = sum_d WoT[i'][d] * xb[j][d]  (A=[m][k], B=[n][k]
// rows, exactly the verified k_gemm operand convention).  Softmax over i' needs
// only 2 shuffles (rows are in-lane p + cross-quad).  Cx[i'',d] = sum_j c[i''][j]
// * xt[d][j].  Wo and c enter as bf16 hi+lo pairs -> f32-grade routing math.

__global__ __launch_bounds__(256)
void k_pass(const __hip_bfloat16* __restrict__ xb, const __hip_bfloat16* __restrict__ xt,
            const __hip_bfloat16* __restrict__ wot, float* __restrict__ pcx) {
    __shared__ __align__(16) float c_lds[16][68];   // pitch 68 f32 = 272B

    const int t = threadIdx.x, w = t >> 6, lane = t & 63;
    const int quad = lane >> 4, r = lane & 15;
    const int blk = blockIdx.x, b = blk >> 3, jb = blk & 7;
    const int j0 = jb * 64 + w * 16;

    // ---- phase 1: bl GEMM, D[i'(16) x j(16)] per wave, K = 320
    f32x4 acc = {0.f, 0.f, 0.f, 0.f};
    const ushort* aph = (const ushort*)wot + ((size_t)(b * 2 + 0) * 16 + r) * KP + quad * 8;
    const ushort* apl = aph + 16 * KP;
    const ushort* bp  = (const ushort*)xb + (size_t)(b * 512 + j0 + r) * KP + quad * 8;
#pragma unroll
    for (int ks = 0; ks < 10; ++ks) {
        short8 bf = *(const short8*)(bp  + ks * 32);
        short8 ah = *(const short8*)(aph + ks * 32);
        short8 al = *(const short8*)(apl + ks * 32);
        acc = __builtin_amdgcn_mfma_f32_16x16x32_bf16(ah, bf, acc, 0, 0, 0);
        acc = __builtin_amdgcn_mfma_f32_16x16x32_bf16(al, bf, acc, 0, 0, 0);
    }
    // lane (quad,r) holds bl[i' = quad*4+p][j = j0+r]; rows 10..15 garbage (masked)

    // ---- phase 2: softmax over i' (valid i' < 10)
    float mx;
    if (quad < 2)       mx = fmaxf(fmaxf(acc[0], acc[1]), fmaxf(acc[2], acc[3]));
    else if (quad == 2) mx = fmaxf(acc[0], acc[1]);
    else                mx = -1e30f;
    mx = fmaxf(mx, __shfl_xor(mx, 16, 64));
    mx = fmaxf(mx, __shfl_xor(mx, 32, 64));
    float e0 = (quad < 3) ? __expf(acc[0] - mx) : 0.f;
    float e1 = (quad < 3) ? __expf(acc[1] - mx) : 0.f;
    float e2 = (quad < 2) ? __expf(acc[2] - mx) : 0.f;
    float e3 = (quad < 2) ? __expf(acc[3] - mx) : 0.f;
    float ss = e0 + e1 + e2 + e3;
    ss += __shfl_xor(ss, 16, 64);
    ss += __shfl_xor(ss, 32, 64);
    float inv = 1.f / ss;
    int col = w * 16 + r;
    if (quad < 2) {
        c_lds[quad * 4 + 0][col] = e0 * inv;
        c_lds[quad * 4 + 1][col] = e1 * inv;
        c_lds[quad * 4 + 2][col] = e2 * inv;
        c_lds[quad * 4 + 3][col] = e3 * inv;
    } else if (quad == 2) {
        c_lds[8][col] = e0 * inv;
        c_lds[9][col] = e1 * inv;
    }
    __syncthreads();

    // ---- phase 3: Cx GEMM, D[i''(16) x d(16)] x 5 N-tiles/wave, K = 64 (block j)
    short8 a2h[2], a2l[2];
#pragma unroll
    for (int ks = 0; ks < 2; ++ks) {
        const float* cp = &c_lds[r][ks * 32 + quad * 8];
        union { ushort u[8]; short8 v; } H, L;
#pragma unroll
        for (int e = 0; e < 8; ++e) {
            float cf = cp[e];
            __hip_bfloat16 hh = __float2bfloat16(cf);
            float hf = __bfloat162float(hh);
            __hip_bfloat16 ll = __float2bfloat16(cf - hf);
            H.u[e] = *(ushort*)&hh;
            L.u[e] = *(ushort*)&ll;
        }
        a2h[ks] = H.v; a2l[ks] = L.v;
    }
    f32x4 cacc[5] = {};
#pragma unroll
    for (int nt = 0; nt < 5; ++nt) {
        const ushort* bb = (const ushort*)xt +
            (size_t)(b * KP + (w * 5 + nt) * 16 + r) * 512 + jb * 64 + quad * 8;
        short8 b20 = *(const short8*)(bb);
        short8 b21 = *(const short8*)(bb + 32);
        cacc[nt] = __builtin_amdgcn_mfma_f32_16x16x32_bf16(a2h[0], b20, cacc[nt], 0, 0, 0);
        cacc[nt] = __builtin_amdgcn_mfma_f32_16x16x32_bf16(a2l[0], b20, cacc[nt], 0, 0, 0);
        cacc[nt] = __builtin_amdgcn_mfma_f32_16x16x32_bf16(a2h[1], b21, cacc[nt], 0, 0, 0);
        cacc[nt] = __builtin_amdgcn_mfma_f32_16x16x32_bf16(a2l[1], b21, cacc[nt], 0, 0, 0);
    }
    // write Cx partials, rows i'' < 10 only
    float* pout = pcx + (size_t)(b * 8 + jb) * 10 * KP;
#pragma unroll
    for (int nt = 0; nt < 5; ++nt) {
        int d = (w * 5 + nt) * 16 + r;
        if (quad < 2) {
#pragma unroll
            for (int p = 0; p < 4; ++p) pout[(quad * 4 + p) * KP + d] = cacc[nt][p];
        } else if (quad == 2) {
            pout[8 * KP + d] = cacc[nt][0];
            pout[9 * KP + d] = cacc[nt][1];
        }
    }
}

// ---------------- combine: Cx -> po -> squash -> out; then Wo = W^T.out ----------------
// MODE 0: first (src = sx, Cx = 0.1*sx per i).  MODE 1: mid (src = pcx).
// MODE 2: last (src = pcx, write d_out, skip Wo).  Block = b, 640 threads.

template<int MODE>
__global__ __launch_bounds__(640)
void k_out(const float* __restrict__ src, const float* __restrict__ W,
           const __hip_bfloat16* __restrict__ wt, __hip_bfloat16* __restrict__ wot,
           float* __restrict__ dst) {
    __shared__ __align__(16) float cx[10 * KP];
    __shared__ __align__(16) float outl[MM];
    const int b = blockIdx.x, t = threadIdx.x;

    // phase 1: build Cx[10][320] in LDS
    {
        int dd = (t >= KP) ? t - KP : t;
        int ih = (t >= KP) ? 1 : 0;
        if (MODE == 0) {
            float v = 0.1f * src[b * KP + dd];
#pragma unroll
            for (int kk = 0; kk < 5; ++kk) cx[(2 * kk + ih) * KP + dd] = v;
        } else {
            const float* pp = src + (size_t)b * 8 * 10 * KP;
#pragma unroll
            for (int kk = 0; kk < 5; ++kk) {
                float s = 0.f;
#pragma unroll
                for (int jbk = 0; jbk < 8; ++jbk)
                    s += pp[jbk * 10 * KP + (2 * kk + ih) * KP + dd];
                cx[(2 * kk + ih) * KP + dd] = s;
            }
        }
    }
    __syncthreads();

    // phase 2: po[m] = sum_d Cx[i][d] * wt[m][d]; squash over k within wave (= i)
    const int i = t >> 6;
    const ushort* wrow = (const ushort*)wt + (size_t)t * KP;
    float po = 0.f;
#pragma unroll
    for (int kk = 0; kk < 40; ++kk) {
        union { uint4 q; ushort u[8]; } wv;
        wv.q = *(const uint4*)(wrow + kk * 8);
        const float* cr = cx + i * KP + kk * 8;
#pragma unroll
        for (int e = 0; e < 8; ++e) po += bf2f(wv.u[e]) * cr[e];
    }
    float sq = po * po;
#pragma unroll
    for (int m = 32; m >= 1; m >>= 1) sq += __shfl_xor(sq, m, 64);
    float ov = po * rsqrtf(sq + 1e-7f);
    if (MODE == 2) { dst[(size_t)b * MM + t] = ov; return; }
    outl[t] = ov;
    __syncthreads();

    // phase 3: WoT[b][hi/lo][i][d] = bf16-split of sum_k W[d][i*64+k]*out[i*64+k]
    const int d0 = t >> 1, hW = t & 1;
    float wo[5];
    if (d0 < DD) {
        const float4* wr = (const float4*)(W + (size_t)d0 * MM);
#pragma unroll
        for (int ii = 0; ii < 5; ++ii) {
            int ic = hW * 5 + ii;
            const float4* ol = (const float4*)(outl + ic * 64);
            float s = 0.f;
#pragma unroll
            for (int kk = 0; kk < 16; ++kk) {
                float4 a = wr[ic * 16 + kk];
                float4 o = ol[kk];
                s += a.x * o.x + a.y * o.y + a.z * o.z + a.w * o.w;
            }
            wo[ii] = s;
        }
    } else {
#pragma unroll
        for (int ii = 0; ii < 5; ++ii) wo[ii] = 0.f;
    }
#pragma unroll
    for (int ii = 0; ii < 5; ++ii) {
        int ic = hW * 5 + ii;
        __hip_bfloat16 hh = __float2bfloat16(wo[ii]);
        float hf = __bfloat162float(hh);
        __hip_bfloat16 ll = __float2bfloat16(wo[ii] - hf);
        wot[((size_t)(b * 2 + 0) * 16 + ic) * KP + d0] = hh;
        wot[((size_t)(b * 2 + 1) * 16 + ic) * KP + d0] = ll;
    }
}

// ---------------- launch ----------------

extern "C" void kernel_launch(void* const* d_in, const int* in_sizes, int n_in,
                              void* d_out, int out_size, void* d_ws, size_t ws_size,
                              hipStream_t stream) {
    const float* x = (const float*)d_in[0];   // [128,512,300]
    const float* W = (const float*)d_in[1];   // [1,300,640]
    float* out = (float*)d_out;               // [128,10,64]

    char* ws = (char*)d_ws;
    size_t o = 0;
    __hip_bfloat16* xb  = (__hip_bfloat16*)(ws + o); o += (size_t)BQ * NJ * KP * 2;   // 41.9 MB
    __hip_bfloat16* xt  = (__hip_bfloat16*)(ws + o); o += (size_t)BQ * KP * NJ * 2;   // 41.9 MB
    __hip_bfloat16* wt  = (__hip_bfloat16*)(ws + o); o += (size_t)MM * KP * 2;        // 0.4 MB
    __hip_bfloat16* wot = (__hip_bfloat16*)(ws + o); o += (size_t)BQ * 2 * 16 * KP * 2; // 2.6 MB
    float* pcx = (float*)(ws + o); o += (size_t)BQ * 8 * 10 * KP * 4;                 // 13.1 MB
    float* sx  = (float*)(ws + o); o += (size_t)BQ * KP * 4;                          // 0.16 MB

    k_cast_x<<<(BQ * NJ * 40) / 256, 256, 0, stream>>>(x, xb);
    k_cast_w<<<(MM * KP) / 256, 256, 0, stream>>>(W, wt);
    k_zero<<<(BQ * KP * 4) / (16 * 256), 256, 0, stream>>>((float4*)sx);   // 40 blocks
    k_xt<<<BQ * 40, 256, 0, stream>>>(xb, xt, sx);

    // iteration 0: c uniform -> out_0 = squash(0.1 * sx . W); also WoT(out_0)
    k_out<0><<<BQ, 640, 0, stream>>>(sx, W, wt, wot, nullptr);
    // iterations 1..4
    k_pass<<<BQ * 8, 256, 0, stream>>>(xb, xt, wot, pcx);
    k_out<1><<<BQ, 640, 0, stream>>>(pcx, W, wt, wot, nullptr);
    k_pass<<<BQ * 8, 256, 0, stream>>>(xb, xt, wot, pcx);
    k_out<1><<<BQ, 640, 0, stream>>>(pcx, W, wt, wot, nullptr);
    k_pass<<<BQ * 8, 256, 0, stream>>>(xb, xt, wot, pcx);
    k_out<1><<<BQ, 640, 0, stream>>>(pcx, W, wt, wot, nullptr);
    k_pass<<<BQ * 8, 256, 0, stream>>>(xb, xt, wot, pcx);
    k_out<2><<<BQ, 640, 0, stream>>>(pcx, W, wt, wot, out);
}

// Round 4
// 339.549 us; speedup vs baseline: 1.2544x; 1.2544x over previous
//
#include <hip/hip_runtime.h>
#include <hip/hip_bf16.h>
#include <stdint.h>

// Problem constants
#define BQ 128    // batch
#define NJ 512    // input capsules j
#define DD 300    // input dim
#define NC 10     // num_capsule i
#define DC 64     // dim_capsule k
#define MM 640    // NC*DC
#define KP 320    // K padded (mult of 64)
#define RT 5      // routing iterations

typedef __attribute__((ext_vector_type(8))) short short8;
typedef __attribute__((ext_vector_type(4))) float f32x4;

__device__ inline float bf2f(ushort u) { return __uint_as_float((uint)u << 16); }

// ---------------- cast kernels (unchanged) ----------------

__global__ void k_cast_x(const float* __restrict__ x, __hip_bfloat16* __restrict__ xb) {
    int g = blockIdx.x * 256 + threadIdx.x;      // 65536*40 groups
    int row = g / 40, cg2 = g - row * 40;
    const float* src = x + (size_t)row * DD + cg2 * 8;
    float4 a = make_float4(0.f, 0.f, 0.f, 0.f), b4 = a;
    if (cg2 < 37) { a = *(const float4*)src; b4 = *(const float4*)(src + 4); }
    else if (cg2 == 37) { a = *(const float4*)src; }
    union { ushort u[8]; uint4 v; } o;
    float f[8] = {a.x, a.y, a.z, a.w, b4.x, b4.y, b4.z, b4.w};
#pragma unroll
    for (int e = 0; e < 8; ++e) {
        __hip_bfloat16 hh = __float2bfloat16(f[e]);
        o.u[e] = *(ushort*)&hh;
    }
    *(uint4*)(xb + (size_t)row * KP + cg2 * 8) = o.v;
}

__global__ void k_cast_w(const float* __restrict__ w, __hip_bfloat16* __restrict__ wt) {
    int idx = blockIdx.x * 256 + threadIdx.x;
    int m = idx / KP, k = idx - m * KP;
    float v = (k < DD) ? w[(size_t)k * MM + m] : 0.f;
    wt[idx] = __float2bfloat16(v);
}

__global__ void k_zero(float4* __restrict__ p) {   // zero sx (ws re-poisoned each call)
    p[blockIdx.x * 256 + threadIdx.x] = make_float4(0.f, 0.f, 0.f, 0.f);
}

// ---------------- transpose xb -> xt, fused column-sum sx ----------------
// block = (b, jt 0..7, dt 0..4): 64j x 64d tile. sx[b][d] = sum_j x[b,j,d].

__global__ __launch_bounds__(256)
void k_xt(const __hip_bfloat16* __restrict__ xb, __hip_bfloat16* __restrict__ xt,
          float* __restrict__ sx) {
    __shared__ ushort lt[64][76];                 // pitch 76 u16 = 152B (b64-aligned)
    int blk = blockIdx.x;
    int b = blk / 40, rem = blk - b * 40, jt = rem / 5, dt = rem - (rem / 5) * 5;
    int t = threadIdx.x;
    int r = t >> 2, c = t & 3;
#pragma unroll
    for (int h = 0; h < 2; ++h) {
        uint4 v = *(const uint4*)((const ushort*)xb +
            (size_t)(b * 512 + jt * 64 + r) * KP + dt * 64 + (c + 4 * h) * 8);
        *(uint2*)&lt[r][(c + 4 * h) * 8]     = make_uint2(v.x, v.y);
        *(uint2*)&lt[r][(c + 4 * h) * 8 + 4] = make_uint2(v.z, v.w);
    }
    __syncthreads();
    int dr = t >> 2;
    float s = 0.f;
#pragma unroll
    for (int h = 0; h < 2; ++h) {
        int jc = c + 4 * h;
        union { ushort u[8]; uint4 v; } o;
#pragma unroll
        for (int e = 0; e < 8; ++e) o.u[e] = lt[jc * 8 + e][dr];
        *(uint4*)((ushort*)xt + (size_t)(b * KP + dt * 64 + dr) * 512 + jt * 64 + jc * 8) = o.v;
#pragma unroll
        for (int e = 0; e < 8; ++e) s += bf2f(o.u[e]);
    }
    s += __shfl_xor(s, 1, 64);
    s += __shfl_xor(s, 2, 64);
    if (c == 0) atomicAdd(&sx[b * KP + dt * 64 + dr], s);
}

// ---------------- routing pass: bl-MFMA -> softmax -> Cx-MFMA ----------------
// block = (b, jb 0..7) covering 64 j; 256 threads = 4 waves, wave w owns j-tile
// j0 = jb*64 + w*16.  v4 change: phase-3 B operand (xt) is prefetched at kernel
// entry — those loads are independent of phases 1-2, and the compiler's vmcnt
// drain at the softmax barrier would otherwise serialize them AFTER it.

__global__ __launch_bounds__(256)
void k_pass(const __hip_bfloat16* __restrict__ xb, const __hip_bfloat16* __restrict__ xt,
            const __hip_bfloat16* __restrict__ wot, float* __restrict__ pcx) {
    __shared__ __align__(16) float c_lds[16][68];   // pitch 68 f32 = 272B

    const int t = threadIdx.x, w = t >> 6, lane = t & 63;
    const int quad = lane >> 4, r = lane & 15;
    const int blk = blockIdx.x, b = blk >> 3, jb = blk & 7;
    const int j0 = jb * 64 + w * 16;

    // ---- prefetch phase-3 B operand (xt), independent of phases 1-2
    short8 b2[5][2];
#pragma unroll
    for (int nt = 0; nt < 5; ++nt) {
        const ushort* bb = (const ushort*)xt +
            (size_t)(b * KP + (w * 5 + nt) * 16 + r) * 512 + jb * 64 + quad * 8;
        b2[nt][0] = *(const short8*)(bb);
        b2[nt][1] = *(const short8*)(bb + 32);
    }

    // ---- phase 1: bl GEMM, D[i'(16) x j(16)] per wave, K = 320
    f32x4 acc = {0.f, 0.f, 0.f, 0.f};
    const ushort* aph = (const ushort*)wot + ((size_t)(b * 2 + 0) * 16 + r) * KP + quad * 8;
    const ushort* apl = aph + 16 * KP;
    const ushort* bp  = (const ushort*)xb + (size_t)(b * 512 + j0 + r) * KP + quad * 8;
#pragma unroll
    for (int ks = 0; ks < 10; ++ks) {
        short8 bf = *(const short8*)(bp  + ks * 32);
        short8 ah = *(const short8*)(aph + ks * 32);
        short8 al = *(const short8*)(apl + ks * 32);
        acc = __builtin_amdgcn_mfma_f32_16x16x32_bf16(ah, bf, acc, 0, 0, 0);
        acc = __builtin_amdgcn_mfma_f32_16x16x32_bf16(al, bf, acc, 0, 0, 0);
    }
    // lane (quad,r) holds bl[i' = quad*4+p][j = j0+r]; rows 10..15 garbage (masked)

    // ---- phase 2: softmax over i' (valid i' < 10)
    float mx;
    if (quad < 2)       mx = fmaxf(fmaxf(acc[0], acc[1]), fmaxf(acc[2], acc[3]));
    else if (quad == 2) mx = fmaxf(acc[0], acc[1]);
    else                mx = -1e30f;
    mx = fmaxf(mx, __shfl_xor(mx, 16, 64));
    mx = fmaxf(mx, __shfl_xor(mx, 32, 64));
    float e0 = (quad < 3) ? __expf(acc[0] - mx) : 0.f;
    float e1 = (quad < 3) ? __expf(acc[1] - mx) : 0.f;
    float e2 = (quad < 2) ? __expf(acc[2] - mx) : 0.f;
    float e3 = (quad < 2) ? __expf(acc[3] - mx) : 0.f;
    float ss = e0 + e1 + e2 + e3;
    ss += __shfl_xor(ss, 16, 64);
    ss += __shfl_xor(ss, 32, 64);
    float inv = 1.f / ss;
    int col = w * 16 + r;
    if (quad < 2) {
        c_lds[quad * 4 + 0][col] = e0 * inv;
        c_lds[quad * 4 + 1][col] = e1 * inv;
        c_lds[quad * 4 + 2][col] = e2 * inv;
        c_lds[quad * 4 + 3][col] = e3 * inv;
    } else if (quad == 2) {
        c_lds[8][col] = e0 * inv;
        c_lds[9][col] = e1 * inv;
    }
    __syncthreads();

    // ---- phase 3: Cx GEMM, D[i''(16) x d(16)] x 5 N-tiles/wave, K = 64 (block j)
    short8 a2h[2], a2l[2];
#pragma unroll
    for (int ks = 0; ks < 2; ++ks) {
        const float* cp = &c_lds[r][ks * 32 + quad * 8];
        union { ushort u[8]; short8 v; } H, L;
#pragma unroll
        for (int e = 0; e < 8; ++e) {
            float cf = cp[e];
            __hip_bfloat16 hh = __float2bfloat16(cf);
            float hf = __bfloat162float(hh);
            __hip_bfloat16 ll = __float2bfloat16(cf - hf);
            H.u[e] = *(ushort*)&hh;
            L.u[e] = *(ushort*)&ll;
        }
        a2h[ks] = H.v; a2l[ks] = L.v;
    }
    f32x4 cacc[5] = {};
#pragma unroll
    for (int nt = 0; nt < 5; ++nt) {
        cacc[nt] = __builtin_amdgcn_mfma_f32_16x16x32_bf16(a2h[0], b2[nt][0], cacc[nt], 0, 0, 0);
        cacc[nt] = __builtin_amdgcn_mfma_f32_16x16x32_bf16(a2l[0], b2[nt][0], cacc[nt], 0, 0, 0);
        cacc[nt] = __builtin_amdgcn_mfma_f32_16x16x32_bf16(a2h[1], b2[nt][1], cacc[nt], 0, 0, 0);
        cacc[nt] = __builtin_amdgcn_mfma_f32_16x16x32_bf16(a2l[1], b2[nt][1], cacc[nt], 0, 0, 0);
    }
    // write Cx partials, rows i'' < 10 only
    float* pout = pcx + (size_t)(b * 8 + jb) * 10 * KP;
#pragma unroll
    for (int nt = 0; nt < 5; ++nt) {
        int d = (w * 5 + nt) * 16 + r;
        if (quad < 2) {
#pragma unroll
            for (int p = 0; p < 4; ++p) pout[(quad * 4 + p) * KP + d] = cacc[nt][p];
        } else if (quad == 2) {
            pout[8 * KP + d] = cacc[nt][0];
            pout[9 * KP + d] = cacc[nt][1];
        }
    }
}

// ---------------- combine: Cx -> po -> squash -> out; then Wo = W^T.out ----------------
// v4: grid (b,i) = 1280 blocks x 256 thr (was 128 x 640 = half the chip idle,
// 48.5us latency chain). Per block: reduce 8 jb-partials of one (b,i) row,
// 4-wave d-split dot for po[k], wave-0 squash, per-thread-d Wo with contiguous
// W-row reads (L2-hot: all 128 b share each i-slice).
// MODE 0: first (src = sx, cx = 0.1*sx).  MODE 1: mid.  MODE 2: last (write out).

template<int MODE>
__global__ __launch_bounds__(256)
void k_out(const float* __restrict__ src, const float* __restrict__ W,
           const __hip_bfloat16* __restrict__ wt, __hip_bfloat16* __restrict__ wot,
           float* __restrict__ dst) {
    __shared__ __align__(16) float cx[KP];
    __shared__ __align__(16) float red[4 * 64];
    __shared__ __align__(16) float outl[DC];
    const int blk = blockIdx.x;
    const int b = blk / 10, i = blk - b * 10;
    const int t = threadIdx.x, w = t >> 6, lane = t & 63;

    // phase 1: cx[d] for this (b,i)
    for (int d = t; d < KP; d += 256) {
        float v;
        if (MODE == 0) {
            v = 0.1f * src[(size_t)b * KP + d];
        } else {
            const float* pp = src + (size_t)b * 8 * 10 * KP + (size_t)i * KP + d;
            v = 0.f;
#pragma unroll
            for (int jb = 0; jb < 8; ++jb) v += pp[(size_t)jb * 10 * KP];
        }
        cx[d] = v;
    }
    __syncthreads();

    // phase 2: po[k] = sum_d cx[d]*wt[i*64+k][d]; d split over 4 waves (80 each)
    {
        const ushort* wr = (const ushort*)wt + (size_t)(i * 64 + lane) * KP + w * 80;
        const float* cr = cx + w * 80;
        float pp = 0.f;
#pragma unroll
        for (int kk = 0; kk < 10; ++kk) {
            union { uint4 q; ushort u[8]; } wv;
            wv.q = *(const uint4*)(wr + kk * 8);
#pragma unroll
            for (int e = 0; e < 8; ++e) pp += bf2f(wv.u[e]) * cr[kk * 8 + e];
        }
        red[w * 64 + lane] = pp;
    }
    __syncthreads();
    if (w == 0) {
        float po = red[lane] + red[64 + lane] + red[128 + lane] + red[192 + lane];
        float sq = po * po;
#pragma unroll
        for (int m = 32; m >= 1; m >>= 1) sq += __shfl_xor(sq, m, 64);
        float ov = po * rsqrtf(sq + 1e-7f);
        if (MODE == 2) dst[(size_t)b * MM + i * 64 + lane] = ov;
        else           outl[lane] = ov;
    }
    if (MODE == 2) return;
    __syncthreads();

    // phase 3: Wo[d] = sum_k W[d][i*64+k]*outl[k]; write hi/lo bf16 split
    for (int d = t; d < KP; d += 256) {
        float s = 0.f;
        if (d < DD) {
            const float4* wr4 = (const float4*)(W + (size_t)d * MM + i * 64);
            const float4* ol4 = (const float4*)outl;
#pragma unroll
            for (int kk = 0; kk < 16; ++kk) {
                float4 a = wr4[kk];
                float4 o = ol4[kk];
                s += a.x * o.x + a.y * o.y + a.z * o.z + a.w * o.w;
            }
        }
        __hip_bfloat16 hh = __float2bfloat16(s);
        float hf = __bfloat162float(hh);
        __hip_bfloat16 ll = __float2bfloat16(s - hf);
        wot[((size_t)(b * 2 + 0) * 16 + i) * KP + d] = hh;
        wot[((size_t)(b * 2 + 1) * 16 + i) * KP + d] = ll;
    }
}

// ---------------- launch ----------------

extern "C" void kernel_launch(void* const* d_in, const int* in_sizes, int n_in,
                              void* d_out, int out_size, void* d_ws, size_t ws_size,
                              hipStream_t stream) {
    const float* x = (const float*)d_in[0];   // [128,512,300]
    const float* W = (const float*)d_in[1];   // [1,300,640]
    float* out = (float*)d_out;               // [128,10,64]

    char* ws = (char*)d_ws;
    size_t o = 0;
    __hip_bfloat16* xb  = (__hip_bfloat16*)(ws + o); o += (size_t)BQ * NJ * KP * 2;   // 41.9 MB
    __hip_bfloat16* xt  = (__hip_bfloat16*)(ws + o); o += (size_t)BQ * KP * NJ * 2;   // 41.9 MB
    __hip_bfloat16* wt  = (__hip_bfloat16*)(ws + o); o += (size_t)MM * KP * 2;        // 0.4 MB
    __hip_bfloat16* wot = (__hip_bfloat16*)(ws + o); o += (size_t)BQ * 2 * 16 * KP * 2; // 2.6 MB
    float* pcx = (float*)(ws + o); o += (size_t)BQ * 8 * 10 * KP * 4;                 // 13.1 MB
    float* sx  = (float*)(ws + o); o += (size_t)BQ * KP * 4;                          // 0.16 MB

    k_cast_x<<<(BQ * NJ * 40) / 256, 256, 0, stream>>>(x, xb);
    k_cast_w<<<(MM * KP) / 256, 256, 0, stream>>>(W, wt);
    k_zero<<<(BQ * KP * 4) / (16 * 256), 256, 0, stream>>>((float4*)sx);   // 40 blocks
    k_xt<<<BQ * 40, 256, 0, stream>>>(xb, xt, sx);

    // iteration 0: c uniform -> out_0 = squash(0.1 * sx . W); also WoT(out_0)
    k_out<0><<<BQ * 10, 256, 0, stream>>>(sx, W, wt, wot, nullptr);
    // iterations 1..4
    k_pass<<<BQ * 8, 256, 0, stream>>>(xb, xt, wot, pcx);
    k_out<1><<<BQ * 10, 256, 0, stream>>>(pcx, W, wt, wot, nullptr);
    k_pass<<<BQ * 8, 256, 0, stream>>>(xb, xt, wot, pcx);
    k_out<1><<<BQ * 10, 256, 0, stream>>>(pcx, W, wt, wot, nullptr);
    k_pass<<<BQ * 8, 256, 0, stream>>>(xb, xt, wot, pcx);
    k_out<1><<<BQ * 10, 256, 0, stream>>>(pcx, W, wt, wot, nullptr);
    k_pass<<<BQ * 8, 256, 0, stream>>>(xb, xt, wot, pcx);
    k_out<2><<<BQ * 10, 256, 0, stream>>>(pcx, W, wt, wot, out);
}